// Round 6
// baseline (210.133 us; speedup 1.0000x reference)
//
#include <hip/hip_runtime.h>

#define N_NODES 50000
#define N_EDGES 800000
#define CAP 64
#define ZROW 50000   // dedicated all-zero row id in t1l / t2l / p
#define BSTRIDE 96   // bucket row stride in u16 units (192 B): [cnt 4B|pad 12B|ids 128B|tail]

typedef _Float16 f16;
typedef unsigned short u16;
typedef f16 f16x2 __attribute__((ext_vector_type(2)));
typedef f16 f16x4 __attribute__((ext_vector_type(4)));
typedef f16 f16x8 __attribute__((ext_vector_type(8)));
typedef float f32x4 __attribute__((ext_vector_type(4)));

#if __has_builtin(__builtin_amdgcn_fdot2)
#define FDOT2(a, b, c) __builtin_amdgcn_fdot2((a), (b), (c), false)
#else
#define FDOT2(a, b, c) ((c) + (float)(a).x * (float)(b).x + (float)(a).y * (float)(b).y)
#endif

// ---- fillpack: bucket prefill (cnt=0, ids=ZROW), zero-rows, weight packs ----
// w1b: B-frags of [Wl1 | Wr1 | pad]      15 tiles x 4 K-steps (K=128)
// w2b: B-frags of [Wl2 |0(6)| Wr2 |0(6)]  6 tiles x 4 K-steps (K=128, k>=117 -> 0)
// w3b: B-frags of [Wlm|Wlv|Wrm|Wrv]       6 tiles x 2 K-steps (K=64,  k>=42  -> 0)
__global__ void k_fillpack(u16* __restrict__ bucket,
                           f16* __restrict__ t1l, f16* __restrict__ t2l,
                           f16* __restrict__ p,
                           const float* __restrict__ Wl1, const float* __restrict__ Wr1,
                           const float* __restrict__ Wl2, const float* __restrict__ Wr2,
                           const float* __restrict__ Wlm, const float* __restrict__ Wrm,
                           const float* __restrict__ Wlv, const float* __restrict__ Wrv,
                           f16* __restrict__ w1b, f16* __restrict__ w2b,
                           f16* __restrict__ w3b) {
    int gt = blockIdx.x * 256 + threadIdx.x;
    if (gt < N_NODES * 12) {                 // 12 uint4 chunks per 192B row
        int c = gt % 12;
        uint4 val = {0xC350C350u, 0xC350C350u, 0xC350C350u, 0xC350C350u};
        if (c == 0) val.x = 0u;              // cnt = 0
        ((uint4*)bucket)[gt] = val;
    }
    if (blockIdx.x == 2343) {
        int t = threadIdx.x;
        if (t < 64)       ((unsigned*)t1l)[(size_t)ZROW * 64 + t] = 0u;
        else if (t < 96)  ((unsigned*)t2l)[(size_t)ZROW * 32 + (t - 64)] = 0u;
        else if (t < 128) ((unsigned*)p)[(size_t)ZROW * 32 + (t - 96)] = 0u;
    }
    if (gt < 15 * 4 * 64 * 8) {              // w1b
        int f = gt >> 9, r = gt & 511;
        int lane = r >> 3, j = r & 7;
        int nt = f >> 2, s = f & 3;
        int k = s * 32 + (lane >> 4) * 8 + j;
        int col = nt * 16 + (lane & 15);
        float v = 0.f;
        if (col < 117) v = Wl1[k * 117 + col];
        else if (col < 234) v = Wr1[k * 117 + (col - 117)];
        w1b[gt] = (f16)v;
    }
    if (gt < 6 * 4 * 64 * 8) {               // w2b
        int f = gt >> 9, r = gt & 511;
        int lane = r >> 3, j = r & 7;
        int nt = f >> 2, s = f & 3;
        int k = s * 32 + (lane >> 4) * 8 + j;
        int col = nt * 16 + (lane & 15);
        float v = 0.f;
        if (k < 117) {
            if (col < 42)                     v = Wl2[k * 42 + col];
            else if (col >= 48 && col < 90)   v = Wr2[k * 42 + (col - 48)];
        }
        w2b[gt] = (f16)v;
    }
    if (gt < 6 * 2 * 64 * 8) {               // w3b
        int f = gt >> 9, r = gt & 511;
        int lane = r >> 3, j = r & 7;
        int ct = f >> 1, s = f & 1;
        int k = s * 32 + (lane >> 4) * 8 + j;
        int col = ct * 16 + (lane & 15);
        float v = 0.f;
        if (k < 42) {
            if (col < 24)      v = Wlm[k * 24 + col];
            else if (col < 48) v = Wlv[k * 24 + (col - 24)];
            else if (col < 72) v = Wrm[k * 24 + (col - 48)];
            else               v = Wrv[k * 24 + (col - 72)];
        }
        w3b[gt] = (f16)v;
    }
}

// ------- k_bg: edge bucketing FUSED with MFMA gemm1. grid 3125 x 256 (= 800k threads)
// ------- atomic on row-head cnt; id store lands in the SAME 64B line for pos<24.
__global__ __launch_bounds__(256) void k_bg(const int* __restrict__ ei,
                        u16* __restrict__ bucket,
                        const float* __restrict__ x,
                        const f16* __restrict__ w1b, const float* __restrict__ b1,
                        f16* __restrict__ t1l, float* __restrict__ t1r) {
    int t = threadIdx.x;
    int e = blockIdx.x * 256 + t;                // exactly N_EDGES threads
    int se = ei[e];
    int de = ei[N_EDGES + e];
    int pos = atomicAdd((int*)(bucket + (size_t)de * BSTRIDE), 1);

    int base = blockIdx.x * 16;
    __shared__ __align__(16) f16 xa[16 * 128];   // 4 KB, XOR-swizzled 16B chunks
    {   // stage x tile -> f16 LDS
        int row = t >> 4, kc = t & 15;
        const float4* xp = (const float4*)(x + (size_t)(base + row) * 128 + kc * 8);
        float4 x0 = xp[0], x1 = xp[1];
        f16x8 hv;
        hv[0] = (f16)x0.x; hv[1] = (f16)x0.y; hv[2] = (f16)x0.z; hv[3] = (f16)x0.w;
        hv[4] = (f16)x1.x; hv[5] = (f16)x1.y; hv[6] = (f16)x1.z; hv[7] = (f16)x1.w;
        int byte = row * 256 + ((kc ^ (row & 7)) << 4);
        *(f16x8*)((char*)xa + byte) = hv;
    }
    __syncthreads();
    int lane = t & 63, w = t >> 6;
    int hi = lane >> 4, lo = lane & 15;
    f16x8 a[4];
#pragma unroll
    for (int s = 0; s < 4; ++s) {
        int kchunk = s * 4 + hi;
        int byte = lo * 256 + ((kchunk ^ (lo & 7)) << 4);
        a[s] = *(const f16x8*)((const char*)xa + byte);
    }
    int ntiles = (w < 3) ? 4 : 3;
    for (int i = 0; i < ntiles; ++i) {
        int nt = w * 4 + i;
        const f16x8* bp = (const f16x8*)w1b + (size_t)(nt * 4) * 64 + lane;
        f32x4 acc = {0.f, 0.f, 0.f, 0.f};
#pragma unroll
        for (int s = 0; s < 4; ++s)
            acc = __builtin_amdgcn_mfma_f32_16x16x32_f16(a[s], bp[s * 64], acc, 0, 0, 0);
        int gcol = nt * 16 + lo;
#pragma unroll
        for (int r = 0; r < 4; ++r) {
            int grow = base + hi * 4 + r;
            float val = acc[r];
            if (gcol < 117) {
                t1l[(size_t)grow * 128 + gcol] = (f16)val;
            } else if (nt == 7) {
                t1l[(size_t)grow * 128 + gcol] = (f16)0.f;
            }
            if (gcol >= 117) {
                int c2 = gcol - 117;
                if (c2 < 117)      t1r[(size_t)grow * 120 + c2] = val + b1[c2];
                else if (c2 < 120) t1r[(size_t)grow * 120 + c2] = 0.f;
            }
        }
    }
    if (pos < CAP) bucket[(size_t)de * BSTRIDE + 8 + pos] = (u16)se;  // same line as cnt (pos<24)
}

// ---- fused1: block 512 (8 waves), 32-node tile. Wave gathers 4 nodes (15 lanes x
// ---- 16B): h1 = relu(gather(t1l)/deg + t1r) -> swizzled f16 LDS [32][128].
// ---- Then 12 MFMA jobs (2 row-halves x 6 col-tiles) over [Wl2|0|Wr2|0]. grid 1563
__global__ __launch_bounds__(512) void k_fused1(
        const f16* __restrict__ t1l, const float* __restrict__ t1r,
        const u16* __restrict__ bucket,
        const f16* __restrict__ w2b, const float* __restrict__ b2,
        f16* __restrict__ t2l, float* __restrict__ s2) {
    __shared__ __align__(16) f16 h1[32 * 128];   // 8 KB
    __shared__ __align__(16) u16 ids[32 * 72];   // padded rows (72 u16)
    __shared__ int cnts[32];
    int t = threadIdx.x;
    int lane = t & 63, w = t >> 6;
    int tilebase = blockIdx.x * 32;
    if (t < 288) {                               // stage 32 rows x 9 uint4 (cnt+ids)
        int row = t / 9, c = t % 9;
        uint4 q = *(const uint4*)(bucket + (size_t)(tilebase + row) * BSTRIDE + c * 8);
        if (c == 0) cnts[row] = (int)q.x;
        else *(uint4*)(ids + row * 72 + (c - 1) * 8) = q;
    }
    __syncthreads();
    int g = (lane < 60) ? (lane / 15) : 3;
    int d = (lane < 60) ? (lane - g * 15) : 14;
    int nl = w * 4 + g;
    int i_my = tilebase + nl;
    int c = (i_my < N_NODES && lane < 60) ? cnts[nl] : 0;
    int n = min(c, CAP);
    float deg = fmaxf((float)c, 1.f);
    int n0 = __builtin_amdgcn_readlane(n, 0),  n1 = __builtin_amdgcn_readlane(n, 15);
    int n2 = __builtin_amdgcn_readlane(n, 30), n3 = __builtin_amdgcn_readlane(n, 45);
    int nmax = max(max(n0, n1), max(n2, n3));
    float acc[8] = {0.f, 0.f, 0.f, 0.f, 0.f, 0.f, 0.f, 0.f};
    const char* tb = (const char*)t1l;
    unsigned doff = (unsigned)d * 16;
    const f16x2 e10 = {(f16)1.f, (f16)0.f};
    const f16x2 e01 = {(f16)0.f, (f16)1.f};
    int idb = nl * 72;
    for (int e0 = 0; e0 < nmax; e0 += 8) {
        f16x8 v[8];
#pragma unroll
        for (int u = 0; u < 8; ++u) {
            unsigned id = ids[idb + e0 + u];     // slots >= count hold ZROW
            v[u] = *(const f16x8*)(tb + id * 256u + doff);
        }
#pragma unroll
        for (int u = 0; u < 8; ++u) {
            const f16x2* pv = (const f16x2*)&v[u];
#pragma unroll
            for (int j = 0; j < 4; ++j) {
                acc[2 * j]     = FDOT2(pv[j], e10, acc[2 * j]);
                acc[2 * j + 1] = FDOT2(pv[j], e01, acc[2 * j + 1]);
            }
        }
    }
    if (lane < 60) {
        int i_ld = (i_my < N_NODES) ? i_my : 0;
        const float4* sp = (const float4*)(t1r + (size_t)i_ld * 120 + 8 * d);
        float4 s0 = sp[0], s1 = sp[1];
        float sv[8] = {s0.x, s0.y, s0.z, s0.w, s1.x, s1.y, s1.z, s1.w};
        f16x8 hv;
#pragma unroll
        for (int j = 0; j < 8; ++j) hv[j] = (f16)fmaxf(acc[j] / deg + sv[j], 0.f);
        int byte = nl * 256 + ((d ^ (nl & 7)) << 4);
        *(f16x8*)((char*)h1 + byte) = hv;
    } else {                                     // zero chunk 15 (cols 120..127)
        int row = w * 4 + (lane - 60);
        int byte = row * 256 + ((15 ^ (row & 7)) << 4);
        f16x8 z = {};
        *(f16x8*)((char*)h1 + byte) = z;
    }
    __syncthreads();
    int lo = lane & 15, hi = lane >> 4;
    for (int jj = w; jj < 12; jj += 8) {
        int ct = jj >> 1, rh = jj & 1;
        int row = rh * 16 + lo;
        f16x8 a[4];
#pragma unroll
        for (int s = 0; s < 4; ++s) {
            int kc = s * 4 + hi;
            a[s] = *(const f16x8*)((const char*)h1 + row * 256 + ((kc ^ (row & 7)) << 4));
        }
        const f16x8* bp = (const f16x8*)w2b + (size_t)(ct * 4) * 64 + lane;
        f32x4 acc4 = {0.f, 0.f, 0.f, 0.f};
#pragma unroll
        for (int s = 0; s < 4; ++s)
            acc4 = __builtin_amdgcn_mfma_f32_16x16x32_f16(a[s], bp[s * 64], acc4, 0, 0, 0);
        int col = ct * 16 + lo;
#pragma unroll
        for (int r = 0; r < 4; ++r) {
            int node = tilebase + rh * 16 + hi * 4 + r;
            if (node < N_NODES) {
                if (col < 48)      t2l[(size_t)node * 64 + col] = (f16)acc4[r];
                else if (col < 90) s2[(size_t)node * 42 + (col - 48)] = acc4[r] + b2[col - 48];
            }
        }
    }
}

// ---- fused2: block 128 (2 waves), 16-node tile. Wave gathers 8 nodes (6 lanes x
// ---- 16B = t2l cols 0..47, 42..47 zero). h2 -> swizzled LDS [16][64].
// ---- MFMA K=64 over [Wlm|Wlv|Wrm|Wrv]: cols<48 -> p, cols>=48 -> out self. grid 3125
__global__ __launch_bounds__(128) void k_fused2(
        const f16* __restrict__ t2l, const float* __restrict__ s2,
        const u16* __restrict__ bucket,
        const f16* __restrict__ w3b,
        const float* __restrict__ bm, const float* __restrict__ bv,
        f16* __restrict__ p, float* __restrict__ out) {
    __shared__ __align__(16) f16 h2[16 * 64];    // 2 KB
    __shared__ __align__(16) u16 ids[16 * 72];
    __shared__ int cnts[16];
    int t = threadIdx.x;
    int lane = t & 63, wv = t >> 6;
    int nb = blockIdx.x * 16;
    for (int s = t; s < 144; s += 128) {         // 16 rows x 9 uint4
        int row = s / 9, c = s % 9;
        uint4 q = *(const uint4*)(bucket + (size_t)(nb + row) * BSTRIDE + c * 8);
        if (c == 0) cnts[row] = (int)q.x;
        else *(uint4*)(ids + row * 72 + (c - 1) * 8) = q;
    }
    __syncthreads();
    int g = (lane < 48) ? (lane / 6) : 7;
    int d = (lane < 48) ? (lane - g * 6) : 5;
    int nl = wv * 8 + g;
    int i_my = nb + nl;
    int c = (lane < 48) ? cnts[nl] : 0;
    int n = min(c, CAP);
    float deg = fmaxf((float)c, 1.f);
    int nmax = n;
#pragma unroll
    for (int m = 1; m < 64; m <<= 1) nmax = max(nmax, __shfl_xor(nmax, m));
    float acc[8] = {0.f, 0.f, 0.f, 0.f, 0.f, 0.f, 0.f, 0.f};
    const char* tb = (const char*)t2l;
    unsigned doff = (unsigned)d * 16;
    const f16x2 e10 = {(f16)1.f, (f16)0.f};
    const f16x2 e01 = {(f16)0.f, (f16)1.f};
    int idb = nl * 72;
    for (int e0 = 0; e0 < nmax; e0 += 8) {
        f16x8 v[8];
#pragma unroll
        for (int u = 0; u < 8; ++u) {
            unsigned id = ids[idb + e0 + u];
            v[u] = *(const f16x8*)(tb + id * 128u + doff);
        }
#pragma unroll
        for (int u = 0; u < 8; ++u) {
            const f16x2* pv = (const f16x2*)&v[u];
#pragma unroll
            for (int j = 0; j < 4; ++j) {
                acc[2 * j]     = FDOT2(pv[j], e10, acc[2 * j]);
                acc[2 * j + 1] = FDOT2(pv[j], e01, acc[2 * j + 1]);
            }
        }
    }
    if (lane < 48) {
        float sv[8];
        if (d < 5) {
            const float4* sp = (const float4*)(s2 + (size_t)i_my * 42 + 8 * d);
            float4 s0 = sp[0], s1 = sp[1];
            sv[0] = s0.x; sv[1] = s0.y; sv[2] = s0.z; sv[3] = s0.w;
            sv[4] = s1.x; sv[5] = s1.y; sv[6] = s1.z; sv[7] = s1.w;
        } else {
            float2 s0 = *(const float2*)(s2 + (size_t)i_my * 42 + 40);
            sv[0] = s0.x; sv[1] = s0.y;
            sv[2] = sv[3] = sv[4] = sv[5] = sv[6] = sv[7] = 0.f;
        }
        f16x8 hv;
#pragma unroll
        for (int j = 0; j < 8; ++j) hv[j] = (f16)fmaxf(acc[j] / deg + sv[j], 0.f);
        int byte = nl * 128 + ((d ^ (nl & 7)) << 4);
        *(f16x8*)((char*)h2 + byte) = hv;
    } else {                                     // zero chunks 6,7 (cols 48..63)
        int j = lane - 48;
        int row = wv * 8 + (j >> 1);
        int chunk = 6 + (j & 1);
        int byte = row * 128 + ((chunk ^ (row & 7)) << 4);
        f16x8 z = {};
        *(f16x8*)((char*)h2 + byte) = z;
    }
    __syncthreads();
    int lo = lane & 15, hi = lane >> 4;
    f16x8 a2[2];
#pragma unroll
    for (int s = 0; s < 2; ++s) {
        int kc = s * 4 + hi;
        a2[s] = *(const f16x8*)((const char*)h2 + lo * 128 + ((kc ^ (lo & 7)) << 4));
    }
#pragma unroll
    for (int i = 0; i < 3; ++i) {
        int ct = wv * 3 + i;
        const f16x8* bp = (const f16x8*)w3b + (size_t)(ct * 2) * 64 + lane;
        f32x4 acc4 = {0.f, 0.f, 0.f, 0.f};
        acc4 = __builtin_amdgcn_mfma_f32_16x16x32_f16(a2[0], bp[0], acc4, 0, 0, 0);
        acc4 = __builtin_amdgcn_mfma_f32_16x16x32_f16(a2[1], bp[64], acc4, 0, 0, 0);
        int col = ct * 16 + lo;
#pragma unroll
        for (int r = 0; r < 4; ++r) {
            int node = nb + hi * 4 + r;
            if (col < 48) {
                p[(size_t)node * 64 + col] = (f16)acc4[r];
            } else {
                int o = col - 48;
                if (o < 24) out[(size_t)node * 24 + o] = acc4[r] + bm[o];
                else out[(size_t)N_NODES * 24 + (size_t)node * 24 + (o - 24)] = acc4[r] + bv[o - 24];
            }
        }
    }
}

// ---- final: block 128 (2 waves), 20 nodes/block. Wave gathers 10 nodes (6 lanes x
// ---- 16B = p cols 0..47) + RMW of self term in out. grid 2500
__global__ __launch_bounds__(128) void k_final(
        const f16* __restrict__ p, const u16* __restrict__ bucket,
        float* __restrict__ out) {
    __shared__ __align__(16) u16 ids[20 * 72];
    __shared__ int cnts[20];
    int t = threadIdx.x;
    int lane = t & 63, wv = t >> 6;
    int nb = blockIdx.x * 20;
    for (int s = t; s < 180; s += 128) {         // 20 rows x 9 uint4
        int row = s / 9, c = s % 9;
        uint4 q = *(const uint4*)(bucket + (size_t)(nb + row) * BSTRIDE + c * 8);
        if (c == 0) cnts[row] = (int)q.x;
        else *(uint4*)(ids + row * 72 + (c - 1) * 8) = q;
    }
    __syncthreads();
    int g = (lane < 60) ? (lane / 6) : 9;
    int d = (lane < 60) ? (lane - g * 6) : 5;
    int nl = wv * 10 + g;
    int i_my = nb + nl;
    int c = (lane < 60) ? cnts[nl] : 0;
    int n = min(c, CAP);
    float deg = fmaxf((float)c, 1.f);
    int nmax = n;
#pragma unroll
    for (int m = 1; m < 64; m <<= 1) nmax = max(nmax, __shfl_xor(nmax, m));
    float acc[8] = {0.f, 0.f, 0.f, 0.f, 0.f, 0.f, 0.f, 0.f};
    const char* pb = (const char*)p;
    unsigned doff = (unsigned)d * 16;
    const f16x2 e10 = {(f16)1.f, (f16)0.f};
    const f16x2 e01 = {(f16)0.f, (f16)1.f};
    int idb = nl * 72;
    for (int e0 = 0; e0 < nmax; e0 += 8) {
        f16x8 v[8];
#pragma unroll
        for (int u = 0; u < 8; ++u) {
            unsigned id = ids[idb + e0 + u];
            v[u] = *(const f16x8*)(pb + id * 128u + doff);
        }
#pragma unroll
        for (int u = 0; u < 8; ++u) {
            const f16x2* pv = (const f16x2*)&v[u];
#pragma unroll
            for (int j = 0; j < 4; ++j) {
                acc[2 * j]     = FDOT2(pv[j], e10, acc[2 * j]);
                acc[2 * j + 1] = FDOT2(pv[j], e01, acc[2 * j + 1]);
            }
        }
    }
    if (lane < 60) {
        float rdeg = 1.f / deg;
        size_t base = (d < 3) ? ((size_t)i_my * 24 + 8 * d)
                              : ((size_t)N_NODES * 24 + (size_t)i_my * 24 + 8 * (d - 3));
        float4 o0 = *(const float4*)(out + base);
        float4 o1 = *(const float4*)(out + base + 4);
        o0.x += acc[0] * rdeg; o0.y += acc[1] * rdeg;
        o0.z += acc[2] * rdeg; o0.w += acc[3] * rdeg;
        o1.x += acc[4] * rdeg; o1.y += acc[5] * rdeg;
        o1.z += acc[6] * rdeg; o1.w += acc[7] * rdeg;
        *(float4*)(out + base) = o0;
        *(float4*)(out + base + 4) = o1;
    }
}

extern "C" void kernel_launch(void* const* d_in, const int* in_sizes, int n_in,
                              void* d_out, int out_size, void* d_ws, size_t ws_size,
                              hipStream_t stream) {
    const float* x   = (const float*)d_in[0];
    const int*   ei  = (const int*)d_in[1];
    const float* Wl1 = (const float*)d_in[2];
    const float* Wr1 = (const float*)d_in[3];
    const float* b1  = (const float*)d_in[4];
    const float* Wl2 = (const float*)d_in[5];
    const float* Wr2 = (const float*)d_in[6];
    const float* b2  = (const float*)d_in[7];
    const float* Wlm = (const float*)d_in[8];
    const float* Wrm = (const float*)d_in[9];
    const float* bm  = (const float*)d_in[10];
    const float* Wlv = (const float*)d_in[11];
    const float* Wrv = (const float*)d_in[12];
    const float* bv  = (const float*)d_in[13];
    float* out = (float*)d_out;

    // workspace layout (bytes):
    //   bucket @ 0          : 50000*192  =  9,600,000  (cnt embedded in row head)
    //   t1l    @ 9,600,000  : 50001*128*2= 12,800,256  -> 22,400,256
    //   t1r    @ 22,400,256 : 50000*120*4= 24,000,000  -> 46,400,256
    //   t2l    @ 46,400,256 : 50001*64*2 =  6,400,128  -> 52,800,384
    //   s2     @ 52,800,384 : 50000*42*4 =  8,400,000  -> 61,200,384
    //     (w1b 61,440 B OVERLAYS s2: consumed by k_bg before fused1 writes s2)
    //   p      @ 61,200,384 : 50001*64*2 =  6,400,128  -> 67,600,512
    //   w2b    @ 67,600,512 : 24,576                   -> 67,625,088
    //   w3b    @ 67,625,088 : 12,288                   -> 67,637,376
    char* ws = (char*)d_ws;
    u16*   bucket = (u16*)(ws);
    f16*   t1l    = (f16*)(ws + 9600000);
    float* t1r    = (float*)(ws + 22400256);
    f16*   t2l    = (f16*)(ws + 46400256);
    float* s2     = (float*)(ws + 52800384);
    f16*   w1b    = (f16*)(ws + 52800384);   // overlays s2 (dead until fused1)
    f16*   p      = (f16*)(ws + 61200384);
    f16*   w2b    = (f16*)(ws + 67600512);
    f16*   w3b    = (f16*)(ws + 67625088);

    k_fillpack<<<2344, 256, 0, stream>>>(bucket, t1l, t2l, p,
                                         Wl1, Wr1, Wl2, Wr2, Wlm, Wrm, Wlv, Wrv,
                                         w1b, w2b, w3b);
    k_bg<<<3125, 256, 0, stream>>>(ei, bucket, x, w1b, b1, t1l, t1r);
    k_fused1<<<1563, 512, 0, stream>>>(t1l, t1r, bucket, w2b, b2, t2l, s2);
    k_fused2<<<3125, 128, 0, stream>>>(t2l, s2, bucket, w3b, bm, bv, p, out);
    k_final<<<2500, 128, 0, stream>>>(p, bucket, out);
}